// Round 4
// baseline (3037.025 us; speedup 1.0000x reference)
//
#include <hip/hip_runtime.h>
#include <hip/hip_bf16.h>

#define N_ 307
#define B_ 64
#define T_ 12
#define H_ 64
#define E_ 10
#define CH_ 14
#define HM_ 16
#define I2_ 66   // 2*DIN + H
#define GO_ 128  // 2*H
#define UO_ 64
#define QG_ (2 * I2_ * GO_)  // 16896
#define QU_ (2 * I2_ * UO_)  // 8448

__device__ __forceinline__ float wsum(float v) {
    #pragma unroll
    for (int off = 32; off; off >>= 1) v += __shfl_xor(v, off);
    return v;
}
__device__ __forceinline__ float wmax(float v) {
    #pragma unroll
    for (int off = 32; off; off >>= 1) v = fmaxf(v, __shfl_xor(v, off));
    return v;
}
__device__ __forceinline__ float sigm(float x) { return 1.f / (1.f + __expf(-x)); }
__device__ __forceinline__ float ftanh(float x) { return 1.f - 2.f / (__expf(2.f * x) + 1.f); }

// ---------------- P0: supports matrix A = 0.5*(adj_n + softmax(relu(E E^T))) ----------------
__global__ void A_kernel(const float* __restrict__ adj, const float* __restrict__ nemb,
                         float* __restrict__ A) {
    const int n = blockIdx.x;
    const int lane = threadIdx.x; // 64
    float en[E_];
    #pragma unroll
    for (int d = 0; d < E_; ++d) en[d] = nemb[n * E_ + d];
    float asum = 0.f;
    for (int m = lane; m < N_; m += 64) asum += adj[n * N_ + m];
    asum = fmaxf(wsum(asum), 1e-6f);
    float g[5]; bool valid[5];
    float mx = -1e30f;
    #pragma unroll
    for (int it = 0; it < 5; ++it) {
        int m = lane + it * 64;
        valid[it] = (m < N_);
        float dt = 0.f;
        if (valid[it]) {
            #pragma unroll
            for (int e = 0; e < E_; ++e) dt += en[e] * nemb[m * E_ + e];
            dt = fmaxf(dt, 0.f);
            mx = fmaxf(mx, dt);
        }
        g[it] = dt;
    }
    mx = wmax(mx);
    float se = 0.f;
    #pragma unroll
    for (int it = 0; it < 5; ++it)
        if (valid[it]) { g[it] = __expf(g[it] - mx); se += g[it]; }
    se = wsum(se);
    float inv = 1.f / se;
    #pragma unroll
    for (int it = 0; it < 5; ++it) {
        int m = lane + it * 64;
        if (valid[it]) A[n * N_ + m] = 0.5f * (adj[n * N_ + m] / asum + g[it] * inv);
    }
}

// ---------------- P1 fused: all per-node generated weights + W12, one launch ----------------
__device__ __forceinline__ float embdot(const float* __restrict__ nemb, int n,
                                        const float* __restrict__ pool, int Q, int q) {
    float a = 0.f;
    #pragma unroll
    for (int d = 0; d < E_; ++d) a += nemb[n * E_ + d] * pool[d * Q + q];
    return a;
}

__global__ __launch_bounds__(256) void gen_kernel(
    const float* __restrict__ nemb,
    const float* __restrict__ gWp, const float* __restrict__ gbp,
    const float* __restrict__ uWp, const float* __restrict__ ubp,
    const float* __restrict__ mwp,
    const float* __restrict__ W1, const float* __restrict__ W2,
    float* __restrict__ gW, float* __restrict__ gb,
    float* __restrict__ uW, float* __restrict__ ub,
    float* __restrict__ wh, float* __restrict__ W12) {
    const int e0 = N_ * QG_;          // gate_W
    const int e1 = e0 + N_ * GO_;     // gate_b
    const int e2 = e1 + N_ * QU_;     // upd_W
    const int e3 = e2 + N_ * UO_;     // upd_b
    const int e4 = e3 + N_ * H_;      // wh
    const int e5 = e4 + H_ * E_;      // W12
    int idx = blockIdx.x * 256 + threadIdx.x;
    if (idx < e0) {
        int n = idx / QG_, q = idx % QG_;
        gW[idx] = embdot(nemb, n, gWp, QG_, q);
    } else if (idx < e1) {
        int i = idx - e0; int n = i / GO_, q = i % GO_;
        gb[i] = embdot(nemb, n, gbp, GO_, q);
    } else if (idx < e2) {
        int i = idx - e1; int n = i / QU_, q = i % QU_;
        uW[i] = embdot(nemb, n, uWp, QU_, q);
    } else if (idx < e3) {
        int i = idx - e2; int n = i / UO_, q = i % UO_;
        ub[i] = embdot(nemb, n, ubp, UO_, q);
    } else if (idx < e4) {
        int i = idx - e3; int n = i / H_, q = i % H_;
        wh[i] = embdot(nemb, n, mwp, H_, q);
    } else if (idx < e5) {
        int i = idx - e4; int j = i / E_, e = i % E_;
        float a = 0.f;
        #pragma unroll
        for (int q = 0; q < HM_; ++q) a += W1[j * HM_ + q] * W2[q * E_ + e];
        W12[i] = a;
    }
}

// ---------------- P2: hypernet fused: x0/x1 planes and emb[t,b,n,10] (h never stored) ----------------
__global__ __launch_bounds__(256) void hyper_kernel(
    const float* __restrict__ hs, const float* __restrict__ src,
    const float* __restrict__ hyper_W, const float* __restrict__ hyper_b,
    const float* __restrict__ wh, const float* __restrict__ W12,
    float* __restrict__ x0, float* __restrict__ x1, float* __restrict__ emb) {
    const int wid = blockIdx.x * 4 + (threadIdx.x >> 6);
    const int lane = threadIdx.x & 63;
    const int t = wid / (B_ * N_);
    const int rem = wid % (B_ * N_);
    const int b = rem / N_;
    const int n = rem % N_;
    float acc = hyper_b[lane];
    #pragma unroll
    for (int c = 0; c < CH_; ++c)
        acc += hs[((b * CH_ + c) * T_ + t) * N_ + n] * hyper_W[c * H_ + lane];
    float h = ftanh(acc);
    float x0v = wsum(h * wh[n * H_ + lane]);
    float my_e = 0.f;
    #pragma unroll
    for (int e = 0; e < E_; ++e) {
        float ve = wsum(h * W12[lane * E_ + e]);
        if (lane == e) my_e = ve;
    }
    if (lane < E_) emb[(size_t)wid * E_ + lane] = my_e;
    if (lane == 0) {
        x0[wid] = x0v;
        x1[wid] = src[(b * T_ + t) * N_ + n];
    }
}

// ---------------- per-step: Wm[b][n][m] = A[n][m]*sigm(emb.nemb)  (+ dmask, aggx folded in) ----------------
__global__ __launch_bounds__(256) void wm_kernel(
    const float* __restrict__ A, const float* __restrict__ emb,
    const float* __restrict__ nemb, const float* __restrict__ x0,
    const float* __restrict__ x1, float* __restrict__ Wm,
    float* __restrict__ dmask, float* __restrict__ aggx, int t) {
    const int wid = __builtin_amdgcn_readfirstlane(blockIdx.x * 4 + (threadIdx.x >> 6));
    const int lane = threadIdx.x & 63;
    const int b = wid / N_;
    const int n = wid % N_;
    const int tbn = (t * B_ + b) * N_ + n;
    const int xb = tbn - n; // (t*B+b)*N
    float et[E_];
    #pragma unroll
    for (int d = 0; d < E_; ++d) et[d] = emb[(size_t)tbn * E_ + d];
    float* wr = Wm + (size_t)(b * N_ + n) * N_;
    float a0 = 0.f, a1 = 0.f;
    #pragma unroll
    for (int c = 0; c < 5; ++c) {
        int m = c * 64 + lane;
        bool v = (m < N_);
        int mc = v ? m : 0;
        float dt = 0.f;
        #pragma unroll
        for (int d = 0; d < E_; ++d) dt += et[d] * nemb[mc * E_ + d];
        float sg = sigm(dt);
        float w = v ? A[n * N_ + mc] * sg : 0.f;
        if (v) {
            wr[m] = w;
            if (m == n) dmask[tbn] = sg;
            a0 += w * x0[xb + mc];
            a1 += w * x1[xb + mc];
        }
    }
    a0 = wsum(a0);
    a1 = wsum(a1);
    if (lane == 0) {
        aggx[(size_t)tbn * 2] = a0;
        aggx[(size_t)tbn * 2 + 1] = a1;
    }
}

// ---------------- per-step: aggS[b,n,:] = sum_m Wm[b,n,m]*Sin[b,m,:]  (W via scalar path) ----------------
__global__ __launch_bounds__(512) void aggS_kernel(
    const float* __restrict__ Wm, const float* __restrict__ Sin,
    float* __restrict__ aggS) {
    __shared__ float s_lds[160 * 64];
    const int tid = threadIdx.x;
    const int lane = tid & 63;
    const int wv = __builtin_amdgcn_readfirstlane(tid >> 6);
    const int b = blockIdx.y;
    const int nb = blockIdx.x * 32 + wv * 4;
    int roff[4];
    #pragma unroll
    for (int r = 0; r < 4; ++r) {
        int nr = nb + r; if (nr > N_ - 1) nr = N_ - 1;
        roff[r] = __builtin_amdgcn_readfirstlane((b * N_ + nr) * N_);
    }
    float acc[4] = {0.f, 0.f, 0.f, 0.f};
    float4* d4 = (float4*)s_lds;
    // ---- half 0: rows 0..159 ----
    {
        const float4* s4 = (const float4*)(Sin + (size_t)b * N_ * H_);
        for (int idx = tid; idx < 160 * 16; idx += 512) d4[idx] = s4[idx];
    }
    __syncthreads();
    #pragma unroll 8
    for (int m = 0; m < 160; ++m) {
        float sv = s_lds[m * 64 + lane];
        #pragma unroll
        for (int r = 0; r < 4; ++r) acc[r] = fmaf(Wm[roff[r] + m], sv, acc[r]);
    }
    __syncthreads();
    // ---- half 1: rows 160..306 ----
    {
        const float4* s4 = (const float4*)(Sin + ((size_t)b * N_ + 160) * H_);
        for (int idx = tid; idx < 147 * 16; idx += 512) d4[idx] = s4[idx];
    }
    __syncthreads();
    #pragma unroll 8
    for (int m = 0; m < 147; ++m) {
        float sv = s_lds[m * 64 + lane];
        #pragma unroll
        for (int r = 0; r < 4; ++r) acc[r] = fmaf(Wm[roff[r] + 160 + m], sv, acc[r]);
    }
    #pragma unroll
    for (int r = 0; r < 4; ++r) {
        int nr = nb + r;
        if (nr < N_) aggS[((size_t)b * N_ + nr) * H_ + lane] = acc[r];
    }
}

// ---------------- per-step: gate matmul -> zs, r ----------------
__global__ __launch_bounds__(256) void gate_mm_kernel(
    const float* __restrict__ gate_W, const float* __restrict__ gate_b,
    const float* __restrict__ x0, const float* __restrict__ x1,
    const float* __restrict__ S, const float* __restrict__ dmask,
    const float* __restrict__ aggx, const float* __restrict__ aggS,
    float* __restrict__ zs, float* __restrict__ rbuf, int t) {
    __shared__ float W_s[132][64];
    __shared__ float xg_s[32][132];
    const int oh = blockIdx.x, bh = blockIdx.y, n = blockIdx.z;
    const int tid = threadIdx.x;
    for (int idx = tid; idx < 132 * 64; idx += 256) {
        int row = idx >> 6, op = idx & 63;
        int col = (op < 32) ? (oh * 32 + op) : (64 + oh * 32 + (op - 32));
        W_s[row][op] = gate_W[(n * 132 + row) * GO_ + col];
    }
    for (int idx = tid; idx < 32 * 132; idx += 256) {
        int bl = idx / 132, i = idx % 132;
        int b = bh * 32 + bl;
        int tb = (t * B_ + b) * N_ + n;
        float v;
        if (i < 66) {
            float xs = (i == 0) ? x0[tb] : (i == 1) ? x1[tb] : S[(b * N_ + n) * 64 + (i - 2)];
            v = dmask[tb] * xs;
        } else {
            int i2 = i - 66;
            v = (i2 < 2) ? aggx[(size_t)tb * 2 + i2] : aggS[(b * N_ + n) * 64 + (i2 - 2)];
        }
        xg_s[bl][i] = v;
    }
    __syncthreads();
    const int bl = tid >> 3, og = tid & 7;
    float acc[8] = {};
    for (int i = 0; i < 132; ++i) {
        float xv = xg_s[bl][i];
        #pragma unroll
        for (int r = 0; r < 8; ++r) acc[r] += xv * W_s[i][og * 8 + r];
    }
    float v[8];
    #pragma unroll
    for (int r = 0; r < 8; ++r) {
        int op = og * 8 + r;
        int col = (op < 32) ? (oh * 32 + op) : (64 + oh * 32 + (op - 32));
        v[r] = sigm(acc[r] + gate_b[n * GO_ + col]);
    }
    __syncthreads();
    float* zr_s = &xg_s[0][0];
    #pragma unroll
    for (int r = 0; r < 8; ++r) zr_s[bl * 64 + og * 8 + r] = v[r];
    __syncthreads();
    for (int idx = tid; idx < 32 * 32; idx += 256) {
        int bl2 = idx >> 5, jl = idx & 31;
        int b = bh * 32 + bl2;
        int j = oh * 32 + jl;
        float z = zr_s[bl2 * 64 + jl];
        float rr = zr_s[bl2 * 64 + 32 + jl];
        int sidx = (b * N_ + n) * 64 + j;
        zs[sidx] = z * S[sidx];
        rbuf[sidx] = rr;
    }
}

// ---------------- per-step: update matmul + state update (in place) ----------------
__global__ __launch_bounds__(256) void upd_mm_kernel(
    const float* __restrict__ upd_W, const float* __restrict__ upd_b,
    const float* __restrict__ x0, const float* __restrict__ x1,
    const float* __restrict__ zsrc, const float* __restrict__ dmask,
    const float* __restrict__ aggx, const float* __restrict__ aggS,
    const float* __restrict__ rbuf, float* __restrict__ S, int t) {
    __shared__ float W_s[132][64];
    __shared__ float xg_s[32][132];
    const int bh = blockIdx.x, n = blockIdx.y;
    const int tid = threadIdx.x;
    for (int idx = tid; idx < 132 * 64; idx += 256) {
        int row = idx >> 6, op = idx & 63;
        W_s[row][op] = upd_W[(n * 132 + row) * UO_ + op];
    }
    for (int idx = tid; idx < 32 * 132; idx += 256) {
        int bl = idx / 132, i = idx % 132;
        int b = bh * 32 + bl;
        int tb = (t * B_ + b) * N_ + n;
        float v;
        if (i < 66) {
            float xs = (i == 0) ? x0[tb] : (i == 1) ? x1[tb] : zsrc[(b * N_ + n) * 64 + (i - 2)];
            v = dmask[tb] * xs;
        } else {
            int i2 = i - 66;
            v = (i2 < 2) ? aggx[(size_t)tb * 2 + i2] : aggS[(b * N_ + n) * 64 + (i2 - 2)];
        }
        xg_s[bl][i] = v;
    }
    __syncthreads();
    const int bl = tid >> 3, og = tid & 7;
    float acc[8] = {};
    for (int i = 0; i < 132; ++i) {
        float xv = xg_s[bl][i];
        #pragma unroll
        for (int r = 0; r < 8; ++r) acc[r] += xv * W_s[i][og * 8 + r];
    }
    const int b = bh * 32 + bl;
    #pragma unroll
    for (int r = 0; r < 8; ++r) {
        int op = og * 8 + r;
        float hc = ftanh(acc[r] + upd_b[n * UO_ + op]);
        int sidx = (b * N_ + n) * 64 + op;
        float rr = rbuf[sidx];
        float sv = S[sidx];
        S[sidx] = rr * sv + (1.f - rr) * hc;
    }
}

// ---------------- final: layernorm + end linear ----------------
__global__ __launch_bounds__(256) void final_kernel(
    const float* __restrict__ S, const float* __restrict__ gamma,
    const float* __restrict__ beta, const float* __restrict__ endW,
    const float* __restrict__ endb, float* __restrict__ out) {
    const int wid = blockIdx.x * 4 + (threadIdx.x >> 6);
    const int lane = threadIdx.x & 63;
    const int b = wid / N_, n = wid % N_;
    float s = S[wid * 64 + lane];
    float mu = wsum(s) * (1.f / 64.f);
    float d = s - mu;
    float var = wsum(d * d) * (1.f / 64.f);
    float xn = d / sqrtf(var + 1e-12f) * gamma[lane] + beta[lane];
    #pragma unroll
    for (int o = 0; o < 12; ++o) {
        float dot = wsum(xn * endW[o * 64 + lane]);
        if (lane == o) out[(b * 12 + o) * N_ + n] = dot + endb[o];
    }
}

extern "C" void kernel_launch(void* const* d_in, const int* in_sizes, int n_in,
                              void* d_out, int out_size, void* d_ws, size_t ws_size,
                              hipStream_t stream) {
    const float* hyper_source = (const float*)d_in[0];
    const float* source       = (const float*)d_in[1];
    const float* adj          = (const float*)d_in[2];
    const float* nemb         = (const float*)d_in[3];
    const float* mwpool       = (const float*)d_in[4];
    const float* hyper_W      = (const float*)d_in[5];
    const float* hyper_b      = (const float*)d_in[6];
    const float* mask_W1      = (const float*)d_in[7];
    const float* mask_W2      = (const float*)d_in[8];
    const float* gate_Wpool   = (const float*)d_in[9];
    const float* gate_bpool   = (const float*)d_in[10];
    const float* upd_Wpool    = (const float*)d_in[11];
    const float* upd_bpool    = (const float*)d_in[12];
    const float* ln_gamma     = (const float*)d_in[13];
    const float* ln_beta      = (const float*)d_in[14];
    const float* end_W        = (const float*)d_in[15];
    const float* end_b        = (const float*)d_in[16];
    float* out = (float*)d_out;

    float* ws = (float*)d_ws;
    size_t off = 0;
    auto alloc = [&](size_t nf) {
        float* p = ws + off;
        off += (nf + 255) & ~(size_t)255;
        return p;
    };
    float* A      = alloc((size_t)N_ * N_);
    float* wh     = alloc((size_t)N_ * H_);
    float* W12    = alloc((size_t)H_ * E_);
    float* gate_W = alloc((size_t)N_ * QG_);
    float* gate_b = alloc((size_t)N_ * GO_);
    float* upd_W  = alloc((size_t)N_ * QU_);
    float* upd_b  = alloc((size_t)N_ * UO_);
    float* x0     = alloc((size_t)T_ * B_ * N_);
    float* x1     = alloc((size_t)T_ * B_ * N_);
    float* emb    = alloc((size_t)T_ * B_ * N_ * E_);
    float* dmask  = alloc((size_t)T_ * B_ * N_);
    float* aggx   = alloc((size_t)T_ * B_ * N_ * 2);
    float* S      = alloc((size_t)B_ * N_ * H_);
    float* zs     = alloc((size_t)B_ * N_ * H_);
    float* rbuf   = alloc((size_t)B_ * N_ * H_);
    float* aggS   = alloc((size_t)B_ * N_ * H_);
    float* Wm     = alloc((size_t)B_ * N_ * N_);   // 24.1 MB, reused each step

    hipMemsetAsync(S, 0, (size_t)B_ * N_ * H_ * sizeof(float), stream);

    A_kernel<<<N_, 64, 0, stream>>>(adj, nemb, A);

    const int gen_total = N_ * QG_ + N_ * GO_ + N_ * QU_ + N_ * UO_ + N_ * H_ + H_ * E_;
    gen_kernel<<<(gen_total + 255) / 256, 256, 0, stream>>>(
        nemb, gate_Wpool, gate_bpool, upd_Wpool, upd_bpool, mwpool, mask_W1, mask_W2,
        gate_W, gate_b, upd_W, upd_b, wh, W12);

    const int nwaves = T_ * B_ * N_; // 235776, divisible by 4
    hyper_kernel<<<nwaves / 4, 256, 0, stream>>>(hyper_source, source, hyper_W, hyper_b, wh,
                                                 W12, x0, x1, emb);

    for (int t = 0; t < T_; ++t) {
        wm_kernel<<<(B_ * N_) / 4, 256, 0, stream>>>(A, emb, nemb, x0, x1, Wm, dmask, aggx, t);
        aggS_kernel<<<dim3(10, B_), 512, 0, stream>>>(Wm, S, aggS);
        gate_mm_kernel<<<dim3(2, 2, N_), 256, 0, stream>>>(gate_W, gate_b, x0, x1, S, dmask,
                                                           aggx, aggS, zs, rbuf, t);
        aggS_kernel<<<dim3(10, B_), 512, 0, stream>>>(Wm, zs, aggS);
        upd_mm_kernel<<<dim3(2, N_), 256, 0, stream>>>(upd_W, upd_b, x0, x1, zs, dmask, aggx,
                                                       aggS, rbuf, S, t);
    }

    final_kernel<<<(B_ * N_) / 4, 256, 0, stream>>>(S, ln_gamma, ln_beta, end_W, end_b, out);
}

// Round 5
// 2303.246 us; speedup vs baseline: 1.3186x; 1.3186x over previous
//
#include <hip/hip_runtime.h>
#include <hip/hip_bf16.h>

#define N_ 307
#define B_ 64
#define T_ 12
#define H_ 64
#define E_ 10
#define CH_ 14
#define HM_ 16
#define I2_ 66   // 2*DIN + H
#define GO_ 128  // 2*H
#define UO_ 64
#define QG_ (2 * I2_ * GO_)  // 16896
#define QU_ (2 * I2_ * UO_)  // 8448
#define TBN_ (T_ * B_ * N_)  // 235776

__device__ __forceinline__ float wsum(float v) {
    #pragma unroll
    for (int off = 32; off; off >>= 1) v += __shfl_xor(v, off);
    return v;
}
__device__ __forceinline__ float wmax(float v) {
    #pragma unroll
    for (int off = 32; off; off >>= 1) v = fmaxf(v, __shfl_xor(v, off));
    return v;
}
__device__ __forceinline__ float sigm(float x) { return 1.f / (1.f + __expf(-x)); }
__device__ __forceinline__ float ftanh(float x) { return 1.f - 2.f / (__expf(2.f * x) + 1.f); }
// wave-broadcast: lane idx is uniform loop var -> v_readlane (no LDS, no gather)
__device__ __forceinline__ float bcast(float v, int l) {
    return __int_as_float(__builtin_amdgcn_readlane(__float_as_int(v), l));
}

// ---------------- P0: supports matrix A = 0.5*(adj_n + softmax(relu(E E^T))) ----------------
__global__ void A_kernel(const float* __restrict__ adj, const float* __restrict__ nemb,
                         float* __restrict__ A) {
    const int n = blockIdx.x;
    const int lane = threadIdx.x; // 64
    float en[E_];
    #pragma unroll
    for (int d = 0; d < E_; ++d) en[d] = nemb[n * E_ + d];
    float asum = 0.f;
    for (int m = lane; m < N_; m += 64) asum += adj[n * N_ + m];
    asum = fmaxf(wsum(asum), 1e-6f);
    float g[5]; bool valid[5];
    float mx = -1e30f;
    #pragma unroll
    for (int it = 0; it < 5; ++it) {
        int m = lane + it * 64;
        valid[it] = (m < N_);
        float dt = 0.f;
        if (valid[it]) {
            #pragma unroll
            for (int e = 0; e < E_; ++e) dt += en[e] * nemb[m * E_ + e];
            dt = fmaxf(dt, 0.f);
            mx = fmaxf(mx, dt);
        }
        g[it] = dt;
    }
    mx = wmax(mx);
    float se = 0.f;
    #pragma unroll
    for (int it = 0; it < 5; ++it)
        if (valid[it]) { g[it] = __expf(g[it] - mx); se += g[it]; }
    se = wsum(se);
    float inv = 1.f / se;
    #pragma unroll
    for (int it = 0; it < 5; ++it) {
        int m = lane + it * 64;
        if (valid[it]) A[n * N_ + m] = 0.5f * (adj[n * N_ + m] / asum + g[it] * inv);
    }
}

// ---------------- P1 fused: all per-node generated weights + W12, one launch ----------------
__device__ __forceinline__ float embdot(const float* __restrict__ nemb, int n,
                                        const float* __restrict__ pool, int Q, int q) {
    float a = 0.f;
    #pragma unroll
    for (int d = 0; d < E_; ++d) a += nemb[n * E_ + d] * pool[d * Q + q];
    return a;
}

__global__ __launch_bounds__(256) void gen_kernel(
    const float* __restrict__ nemb,
    const float* __restrict__ gWp, const float* __restrict__ gbp,
    const float* __restrict__ uWp, const float* __restrict__ ubp,
    const float* __restrict__ mwp,
    const float* __restrict__ W1, const float* __restrict__ W2,
    float* __restrict__ gW, float* __restrict__ gb,
    float* __restrict__ uW, float* __restrict__ ub,
    float* __restrict__ wh_t, float* __restrict__ W12) {
    const int e0 = N_ * QG_;          // gate_W
    const int e1 = e0 + N_ * GO_;     // gate_b
    const int e2 = e1 + N_ * QU_;     // upd_W
    const int e3 = e2 + N_ * UO_;     // upd_b
    const int e4 = e3 + N_ * H_;      // wh (transposed store)
    const int e5 = e4 + H_ * E_;      // W12
    int idx = blockIdx.x * 256 + threadIdx.x;
    if (idx < e0) {
        int n = idx / QG_, q = idx % QG_;
        gW[idx] = embdot(nemb, n, gWp, QG_, q);
    } else if (idx < e1) {
        int i = idx - e0; int n = i / GO_, q = i % GO_;
        gb[i] = embdot(nemb, n, gbp, GO_, q);
    } else if (idx < e2) {
        int i = idx - e1; int n = i / QU_, q = i % QU_;
        uW[i] = embdot(nemb, n, uWp, QU_, q);
    } else if (idx < e3) {
        int i = idx - e2; int n = i / UO_, q = i % UO_;
        ub[i] = embdot(nemb, n, ubp, UO_, q);
    } else if (idx < e4) {
        int i = idx - e3; int n = i / H_, q = i % H_;
        wh_t[q * N_ + n] = embdot(nemb, n, mwp, H_, q);   // transposed: [j][n]
    } else if (idx < e5) {
        int i = idx - e4; int j = i / E_, e = i % E_;
        float a = 0.f;
        #pragma unroll
        for (int q = 0; q < HM_; ++q) a += W1[j * HM_ + q] * W2[q * E_ + e];
        W12[i] = a;
    }
}

// ---------------- P2 v2: lane-parallel hypernet (no shuffles, no LDS) ----------------
// thread = one (t,b,n); j-reduction sequential in registers.
__global__ __launch_bounds__(256) void hyper2_kernel(
    const float* __restrict__ hs, const float* __restrict__ src,
    const float* __restrict__ hyper_W, const float* __restrict__ hyper_b,
    const float* __restrict__ wh_t, const float* __restrict__ W12,
    float* __restrict__ x0, float* __restrict__ x1, float* __restrict__ emb) {
    const int tb = blockIdx.y;           // t*B + b
    const int t = tb / B_, b = tb % B_;
    const int n = blockIdx.x * 256 + threadIdx.x;
    const bool act = (n < N_);
    const int nc = act ? n : N_ - 1;
    float hsv[CH_];
    #pragma unroll
    for (int c = 0; c < CH_; ++c)
        hsv[c] = hs[((b * CH_ + c) * T_ + t) * N_ + nc];   // coalesced over n
    float ax0 = 0.f;
    float ae[E_] = {};
    #pragma unroll 8
    for (int j = 0; j < H_; ++j) {
        float hj = hyper_b[j];                              // uniform (scalar)
        #pragma unroll
        for (int c = 0; c < CH_; ++c) hj = fmaf(hsv[c], hyper_W[c * H_ + j], hj);
        hj = ftanh(hj);
        ax0 = fmaf(hj, wh_t[j * N_ + nc], ax0);             // coalesced over n
        #pragma unroll
        for (int e = 0; e < E_; ++e) ae[e] = fmaf(hj, W12[j * E_ + e], ae[e]);
    }
    if (act) {
        const int tbn = tb * N_ + n;
        x0[tbn] = ax0;
        x1[tbn] = src[(b * T_ + t) * N_ + n];
        #pragma unroll
        for (int e = 0; e < E_; ++e) emb[e * TBN_ + tbn] = ae[e];  // SoA, coalesced
    }
}

// ---------------- per-step: Wm[b][n][m] = A[n][m]*sigm(emb.nemb)  (+ dmask, aggx folded in) ----------------
__global__ __launch_bounds__(256) void wm_kernel(
    const float* __restrict__ A, const float* __restrict__ emb,
    const float* __restrict__ nemb, const float* __restrict__ x0,
    const float* __restrict__ x1, float* __restrict__ Wm,
    float* __restrict__ dmask, float* __restrict__ aggx, int t) {
    const int wid = __builtin_amdgcn_readfirstlane(blockIdx.x * 4 + (threadIdx.x >> 6));
    const int lane = threadIdx.x & 63;
    const int b = wid / N_;
    const int n = wid % N_;
    const int tbn = (t * B_ + b) * N_ + n;
    const int xb = tbn - n; // (t*B+b)*N
    float et[E_];
    #pragma unroll
    for (int d = 0; d < E_; ++d) et[d] = emb[(size_t)d * TBN_ + tbn];  // SoA broadcast
    float* wr = Wm + (size_t)(b * N_ + n) * N_;
    float a0 = 0.f, a1 = 0.f;
    #pragma unroll
    for (int c = 0; c < 5; ++c) {
        int m = c * 64 + lane;
        bool v = (m < N_);
        int mc = v ? m : 0;
        float dt = 0.f;
        #pragma unroll
        for (int d = 0; d < E_; ++d) dt += et[d] * nemb[mc * E_ + d];
        float sg = sigm(dt);
        float w = v ? A[n * N_ + mc] * sg : 0.f;
        if (v) {
            wr[m] = w;
            if (m == n) dmask[tbn] = sg;
            a0 += w * x0[xb + mc];
            a1 += w * x1[xb + mc];
        }
    }
    a0 = wsum(a0);
    a1 = wsum(a1);
    if (lane == 0) {
        aggx[(size_t)tbn * 2] = a0;
        aggx[(size_t)tbn * 2 + 1] = a1;
    }
}

// ---------------- per-step v3: aggS[b,n,:] = sum_m Wm[b,n,m]*Sin[b,m,:] ----------------
// W via coalesced lane loads + v_readlane broadcast; full S[b] staged in LDS (78.6 KB).
__global__ __launch_bounds__(512) void aggS_kernel(
    const float* __restrict__ Wm, const float* __restrict__ Sin,
    float* __restrict__ aggS) {
    __shared__ float s_lds[N_ * 64]; // 19648 floats = 78.6 KB -> 2 blocks/CU
    const int tid = threadIdx.x;
    const int lane = tid & 63;
    const int wv = tid >> 6;
    const int b = blockIdx.y;
    const int nb = blockIdx.x * 32 + wv * 4;
    // stage all 307 rows of S[b] (coalesced float4)
    {
        const float4* s4 = (const float4*)(Sin + (size_t)b * N_ * 64);
        float4* d4 = (float4*)s_lds;
        for (int idx = tid; idx < N_ * 16; idx += 512) d4[idx] = s4[idx];
    }
    __syncthreads();
    int roff[4];
    #pragma unroll
    for (int r = 0; r < 4; ++r) {
        int nr = nb + r; if (nr > N_ - 1) nr = N_ - 1;
        roff[r] = __builtin_amdgcn_readfirstlane((b * N_ + nr) * N_);
    }
    float acc[4] = {0.f, 0.f, 0.f, 0.f};
    #pragma unroll
    for (int ck = 0; ck < 4; ++ck) {
        const int m0 = ck << 6;
        float w0 = Wm[roff[0] + m0 + lane];
        float w1 = Wm[roff[1] + m0 + lane];
        float w2 = Wm[roff[2] + m0 + lane];
        float w3 = Wm[roff[3] + m0 + lane];
        #pragma unroll 8
        for (int mm = 0; mm < 64; ++mm) {
            float sv = s_lds[(m0 + mm) * 64 + lane];
            acc[0] = fmaf(bcast(w0, mm), sv, acc[0]);
            acc[1] = fmaf(bcast(w1, mm), sv, acc[1]);
            acc[2] = fmaf(bcast(w2, mm), sv, acc[2]);
            acc[3] = fmaf(bcast(w3, mm), sv, acc[3]);
        }
    }
    { // tail: m = 256..306 (51)
        const int m0 = 256;
        bool v = (m0 + lane < N_);
        float w0 = v ? Wm[roff[0] + m0 + lane] : 0.f;
        float w1 = v ? Wm[roff[1] + m0 + lane] : 0.f;
        float w2 = v ? Wm[roff[2] + m0 + lane] : 0.f;
        float w3 = v ? Wm[roff[3] + m0 + lane] : 0.f;
        #pragma unroll 8
        for (int mm = 0; mm < 51; ++mm) {
            float sv = s_lds[(m0 + mm) * 64 + lane];
            acc[0] = fmaf(bcast(w0, mm), sv, acc[0]);
            acc[1] = fmaf(bcast(w1, mm), sv, acc[1]);
            acc[2] = fmaf(bcast(w2, mm), sv, acc[2]);
            acc[3] = fmaf(bcast(w3, mm), sv, acc[3]);
        }
    }
    #pragma unroll
    for (int r = 0; r < 4; ++r) {
        int nr = nb + r;
        if (nr < N_) aggS[((size_t)b * N_ + nr) * 64 + lane] = acc[r];
    }
}

// ---------------- per-step: gate matmul -> zs, r ----------------
__global__ __launch_bounds__(256) void gate_mm_kernel(
    const float* __restrict__ gate_W, const float* __restrict__ gate_b,
    const float* __restrict__ x0, const float* __restrict__ x1,
    const float* __restrict__ S, const float* __restrict__ dmask,
    const float* __restrict__ aggx, const float* __restrict__ aggS,
    float* __restrict__ zs, float* __restrict__ rbuf, int t) {
    __shared__ float W_s[132][64];
    __shared__ float xg_s[32][132];
    const int oh = blockIdx.x, bh = blockIdx.y, n = blockIdx.z;
    const int tid = threadIdx.x;
    for (int idx = tid; idx < 132 * 64; idx += 256) {
        int row = idx >> 6, op = idx & 63;
        int col = (op < 32) ? (oh * 32 + op) : (64 + oh * 32 + (op - 32));
        W_s[row][op] = gate_W[(n * 132 + row) * GO_ + col];
    }
    for (int idx = tid; idx < 32 * 132; idx += 256) {
        int bl = idx / 132, i = idx % 132;
        int b = bh * 32 + bl;
        int tb = (t * B_ + b) * N_ + n;
        float v;
        if (i < 66) {
            float xs = (i == 0) ? x0[tb] : (i == 1) ? x1[tb] : S[(b * N_ + n) * 64 + (i - 2)];
            v = dmask[tb] * xs;
        } else {
            int i2 = i - 66;
            v = (i2 < 2) ? aggx[(size_t)tb * 2 + i2] : aggS[(b * N_ + n) * 64 + (i2 - 2)];
        }
        xg_s[bl][i] = v;
    }
    __syncthreads();
    const int bl = tid >> 3, og = tid & 7;
    float acc[8] = {};
    for (int i = 0; i < 132; ++i) {
        float xv = xg_s[bl][i];
        #pragma unroll
        for (int r = 0; r < 8; ++r) acc[r] += xv * W_s[i][og * 8 + r];
    }
    float v[8];
    #pragma unroll
    for (int r = 0; r < 8; ++r) {
        int op = og * 8 + r;
        int col = (op < 32) ? (oh * 32 + op) : (64 + oh * 32 + (op - 32));
        v[r] = sigm(acc[r] + gate_b[n * GO_ + col]);
    }
    __syncthreads();
    float* zr_s = &xg_s[0][0];
    #pragma unroll
    for (int r = 0; r < 8; ++r) zr_s[bl * 64 + og * 8 + r] = v[r];
    __syncthreads();
    for (int idx = tid; idx < 32 * 32; idx += 256) {
        int bl2 = idx >> 5, jl = idx & 31;
        int b = bh * 32 + bl2;
        int j = oh * 32 + jl;
        float z = zr_s[bl2 * 64 + jl];
        float rr = zr_s[bl2 * 64 + 32 + jl];
        int sidx = (b * N_ + n) * 64 + j;
        zs[sidx] = z * S[sidx];
        rbuf[sidx] = rr;
    }
}

// ---------------- per-step: update matmul + state update (in place) ----------------
__global__ __launch_bounds__(256) void upd_mm_kernel(
    const float* __restrict__ upd_W, const float* __restrict__ upd_b,
    const float* __restrict__ x0, const float* __restrict__ x1,
    const float* __restrict__ zsrc, const float* __restrict__ dmask,
    const float* __restrict__ aggx, const float* __restrict__ aggS,
    const float* __restrict__ rbuf, float* __restrict__ S, int t) {
    __shared__ float W_s[132][64];
    __shared__ float xg_s[32][132];
    const int bh = blockIdx.x, n = blockIdx.y;
    const int tid = threadIdx.x;
    for (int idx = tid; idx < 132 * 64; idx += 256) {
        int row = idx >> 6, op = idx & 63;
        W_s[row][op] = upd_W[(n * 132 + row) * UO_ + op];
    }
    for (int idx = tid; idx < 32 * 132; idx += 256) {
        int bl = idx / 132, i = idx % 132;
        int b = bh * 32 + bl;
        int tb = (t * B_ + b) * N_ + n;
        float v;
        if (i < 66) {
            float xs = (i == 0) ? x0[tb] : (i == 1) ? x1[tb] : zsrc[(b * N_ + n) * 64 + (i - 2)];
            v = dmask[tb] * xs;
        } else {
            int i2 = i - 66;
            v = (i2 < 2) ? aggx[(size_t)tb * 2 + i2] : aggS[(b * N_ + n) * 64 + (i2 - 2)];
        }
        xg_s[bl][i] = v;
    }
    __syncthreads();
    const int bl = tid >> 3, og = tid & 7;
    float acc[8] = {};
    for (int i = 0; i < 132; ++i) {
        float xv = xg_s[bl][i];
        #pragma unroll
        for (int r = 0; r < 8; ++r) acc[r] += xv * W_s[i][og * 8 + r];
    }
    const int b = bh * 32 + bl;
    #pragma unroll
    for (int r = 0; r < 8; ++r) {
        int op = og * 8 + r;
        float hc = ftanh(acc[r] + upd_b[n * UO_ + op]);
        int sidx = (b * N_ + n) * 64 + op;
        float rr = rbuf[sidx];
        float sv = S[sidx];
        S[sidx] = rr * sv + (1.f - rr) * hc;
    }
}

// ---------------- final: layernorm + end linear ----------------
__global__ __launch_bounds__(256) void final_kernel(
    const float* __restrict__ S, const float* __restrict__ gamma,
    const float* __restrict__ beta, const float* __restrict__ endW,
    const float* __restrict__ endb, float* __restrict__ out) {
    const int wid = blockIdx.x * 4 + (threadIdx.x >> 6);
    const int lane = threadIdx.x & 63;
    const int b = wid / N_, n = wid % N_;
    float s = S[wid * 64 + lane];
    float mu = wsum(s) * (1.f / 64.f);
    float d = s - mu;
    float var = wsum(d * d) * (1.f / 64.f);
    float xn = d / sqrtf(var + 1e-12f) * gamma[lane] + beta[lane];
    #pragma unroll
    for (int o = 0; o < 12; ++o) {
        float dot = wsum(xn * endW[o * 64 + lane]);
        if (lane == o) out[(b * 12 + o) * N_ + n] = dot + endb[o];
    }
}

extern "C" void kernel_launch(void* const* d_in, const int* in_sizes, int n_in,
                              void* d_out, int out_size, void* d_ws, size_t ws_size,
                              hipStream_t stream) {
    const float* hyper_source = (const float*)d_in[0];
    const float* source       = (const float*)d_in[1];
    const float* adj          = (const float*)d_in[2];
    const float* nemb         = (const float*)d_in[3];
    const float* mwpool       = (const float*)d_in[4];
    const float* hyper_W      = (const float*)d_in[5];
    const float* hyper_b      = (const float*)d_in[6];
    const float* mask_W1      = (const float*)d_in[7];
    const float* mask_W2      = (const float*)d_in[8];
    const float* gate_Wpool   = (const float*)d_in[9];
    const float* gate_bpool   = (const float*)d_in[10];
    const float* upd_Wpool    = (const float*)d_in[11];
    const float* upd_bpool    = (const float*)d_in[12];
    const float* ln_gamma     = (const float*)d_in[13];
    const float* ln_beta      = (const float*)d_in[14];
    const float* end_W        = (const float*)d_in[15];
    const float* end_b        = (const float*)d_in[16];
    float* out = (float*)d_out;

    float* ws = (float*)d_ws;
    size_t off = 0;
    auto alloc = [&](size_t nf) {
        float* p = ws + off;
        off += (nf + 255) & ~(size_t)255;
        return p;
    };
    float* A      = alloc((size_t)N_ * N_);
    float* wh_t   = alloc((size_t)N_ * H_);
    float* W12    = alloc((size_t)H_ * E_);
    float* gate_W = alloc((size_t)N_ * QG_);
    float* gate_b = alloc((size_t)N_ * GO_);
    float* upd_W  = alloc((size_t)N_ * QU_);
    float* upd_b  = alloc((size_t)N_ * UO_);
    float* x0     = alloc((size_t)TBN_);
    float* x1     = alloc((size_t)TBN_);
    float* emb    = alloc((size_t)TBN_ * E_);   // SoA: [e][tbn]
    float* dmask  = alloc((size_t)TBN_);
    float* aggx   = alloc((size_t)TBN_ * 2);
    float* S      = alloc((size_t)B_ * N_ * H_);
    float* zs     = alloc((size_t)B_ * N_ * H_);
    float* rbuf   = alloc((size_t)B_ * N_ * H_);
    float* aggS   = alloc((size_t)B_ * N_ * H_);
    float* Wm     = alloc((size_t)B_ * N_ * N_);   // 24.1 MB, reused each step

    hipMemsetAsync(S, 0, (size_t)B_ * N_ * H_ * sizeof(float), stream);

    A_kernel<<<N_, 64, 0, stream>>>(adj, nemb, A);

    const int gen_total = N_ * QG_ + N_ * GO_ + N_ * QU_ + N_ * UO_ + N_ * H_ + H_ * E_;
    gen_kernel<<<(gen_total + 255) / 256, 256, 0, stream>>>(
        nemb, gate_Wpool, gate_bpool, upd_Wpool, upd_bpool, mwpool, mask_W1, mask_W2,
        gate_W, gate_b, upd_W, upd_b, wh_t, W12);

    hyper2_kernel<<<dim3(2, T_ * B_), 256, 0, stream>>>(hyper_source, source, hyper_W,
                                                        hyper_b, wh_t, W12, x0, x1, emb);

    for (int t = 0; t < T_; ++t) {
        wm_kernel<<<(B_ * N_) / 4, 256, 0, stream>>>(A, emb, nemb, x0, x1, Wm, dmask, aggx, t);
        aggS_kernel<<<dim3(10, B_), 512, 0, stream>>>(Wm, S, aggS);
        gate_mm_kernel<<<dim3(2, 2, N_), 256, 0, stream>>>(gate_W, gate_b, x0, x1, S, dmask,
                                                           aggx, aggS, zs, rbuf, t);
        aggS_kernel<<<dim3(10, B_), 512, 0, stream>>>(Wm, zs, aggS);
        upd_mm_kernel<<<dim3(2, N_), 256, 0, stream>>>(upd_W, upd_b, x0, x1, zs, dmask, aggx,
                                                       aggS, rbuf, S, t);
    }

    final_kernel<<<(B_ * N_) / 4, 256, 0, stream>>>(S, ln_gamma, ln_beta, end_W, end_b, out);
}